// Round 6
// baseline (707.739 us; speedup 1.0000x reference)
//
#include <hip/hip_runtime.h>
#include <hip/hip_fp16.h>

#define NN 100000      // nodes
#define NE 1600000     // edges
#define INC 128        // in channels
#define HID 96         // hidden
#define NG 512         // graphs
#define NB 782         // ceil(NN/128) dst buckets

// ---------------- CSR build ----------------
__global__ void k_zero(int* __restrict__ off, int* __restrict__ bcur) {
    int i = blockIdx.x * blockDim.x + threadIdx.x;
    if (i < NN + 1) off[i] = 0;
    if (i < NB) bcur[i] = 0;
}

__global__ void k_hist(const int* __restrict__ dst, int* __restrict__ off) {
    int e = blockIdx.x * blockDim.x + threadIdx.x;
    if (e < NE) atomicAdd(&off[dst[e] + 1], 1);
}

// 3-phase scan: blockwise scan (1024 elems/block) -> scan block sums -> add
__global__ __launch_bounds__(256) void k_scan1(int* __restrict__ a, int* __restrict__ bsum, int n) {
    __shared__ int s[256];
    int base = blockIdx.x * 1024 + threadIdx.x * 4;
    int v0 = (base + 0 < n) ? a[base + 0] : 0;
    int v1 = (base + 1 < n) ? a[base + 1] : 0;
    int v2 = (base + 2 < n) ? a[base + 2] : 0;
    int v3 = (base + 3 < n) ? a[base + 3] : 0;
    v1 += v0; v2 += v1; v3 += v2;
    s[threadIdx.x] = v3;
    __syncthreads();
    for (int ofs = 1; ofs < 256; ofs <<= 1) {
        int t = (threadIdx.x >= ofs) ? s[threadIdx.x - ofs] : 0;
        __syncthreads();
        s[threadIdx.x] += t;
        __syncthreads();
    }
    int pre = (threadIdx.x > 0) ? s[threadIdx.x - 1] : 0;
    v0 += pre; v1 += pre; v2 += pre; v3 += pre;
    if (base + 0 < n) a[base + 0] = v0;
    if (base + 1 < n) a[base + 1] = v1;
    if (base + 2 < n) a[base + 2] = v2;
    if (base + 3 < n) a[base + 3] = v3;
    if (threadIdx.x == 255) bsum[blockIdx.x] = s[255];
}

__global__ __launch_bounds__(128) void k_scan2(int* __restrict__ bsum, int nb) {
    __shared__ int s[128];
    int v = (threadIdx.x < nb) ? bsum[threadIdx.x] : 0;
    s[threadIdx.x] = v;
    __syncthreads();
    for (int ofs = 1; ofs < 128; ofs <<= 1) {
        int t = (threadIdx.x >= ofs) ? s[threadIdx.x - ofs] : 0;
        __syncthreads();
        s[threadIdx.x] += t;
        __syncthreads();
    }
    if (threadIdx.x < nb) bsum[threadIdx.x] = s[threadIdx.x];  // inclusive
}

__global__ __launch_bounds__(256) void k_scan3(int* __restrict__ a, const int* __restrict__ bsum, int n) {
    int b = blockIdx.x;
    if (b == 0) return;
    int add = bsum[b - 1];
    int base = b * 1024 + threadIdx.x * 4;
#pragma unroll
    for (int j = 0; j < 4; ++j) {
        int idx = base + j;
        if (idx < n) a[idx] += add;
    }
}

// dis[i] = rsqrt(deg_in + selfloop)
__global__ void k_dis(const int* __restrict__ off, float* __restrict__ dis) {
    int i = blockIdx.x * blockDim.x + threadIdx.x;
    if (i < NN) dis[i] = rsqrtf((float)(off[i + 1] - off[i] + 1));
}

// phase 1: append packed {src, dst&127} into the dst-bucket's CSR region.
// bucket b = dst>>7 covers CSR positions [off[b*128], off[(b+1)*128]) exactly.
__global__ void k_bin(const int* __restrict__ src, const int* __restrict__ dst,
                      const int* __restrict__ off, int* __restrict__ bcur,
                      unsigned* __restrict__ tmp) {
    int e = blockIdx.x * blockDim.x + threadIdx.x;
    if (e >= NE) return;
    int s = src[e], d = dst[e];
    int b = d >> 7;
    int p = off[b << 7] + atomicAdd(&bcur[b], 1);
    tmp[p] = (unsigned)s | ((unsigned)(d & 127) << 17);
}

// phase 2: one block per bucket; LDS counters (bucket owns its 128 dst nodes);
// dense writes into the bucket's ~16KB CSR window.
__global__ __launch_bounds__(256) void k_csr(const unsigned* __restrict__ tmp,
                                             const int* __restrict__ off,
                                             const float* __restrict__ dis,
                                             int2* __restrict__ ssrcw) {
    __shared__ int offw[129];
    __shared__ int cnt[128];
    const int base = blockIdx.x << 7;
    for (int i = threadIdx.x; i < 129; i += 256) {
        int idx = base + i;
        if (idx > NN) idx = NN;
        offw[i] = off[idx];
    }
    for (int i = threadIdx.x; i < 128; i += 256) cnt[i] = 0;
    __syncthreads();
    const int beg = offw[0], endb = offw[128];
    for (int j = beg + (int)threadIdx.x; j < endb; j += 256) {
        unsigned u = tmp[j];
        int s = (int)(u & 0x1FFFFu);
        int dl = (int)(u >> 17);
        float w = dis[s] * dis[base + dl];
        int pos = offw[dl] + atomicAdd(&cnt[dl], 1);
        ssrcw[pos] = make_int2(s, __float_as_int(w));
    }
}

// ---------------- register-tiled GEMM: Yh[N,96] (fp16) = X[N,K] @ W[K,96] ----------------
template <int K>
__global__ __launch_bounds__(256) void k_gemm(const float* __restrict__ X,
                                              const float* __restrict__ W,
                                              __half* __restrict__ Yh) {
    __shared__ float xsT[32][64];   // X tile, transposed
    __shared__ float ws[32 * 96];   // W tile (rows contiguous)
    const int tid = threadIdx.x;
    const int row0 = blockIdx.x * 64;
    const int rg = tid >> 4;        // 0..15
    const int cg = tid & 15;        // 0..15
    const int r0 = rg * 4, c0 = cg * 6;
    float acc[4][6] = {};

    const int srow = tid & 63;      // staging row
    const int sq = tid >> 6;        // 0..3

    for (int k0 = 0; k0 < K; k0 += 32) {
        {
            int grow = row0 + srow;
            float4 v = make_float4(0.f, 0.f, 0.f, 0.f);
            float4 u = make_float4(0.f, 0.f, 0.f, 0.f);
            if (grow < NN) {
                v = *(const float4*)&X[(size_t)grow * K + k0 + sq * 4];
                u = *(const float4*)&X[(size_t)grow * K + k0 + (sq + 4) * 4];
            }
            xsT[sq * 4 + 0][srow] = v.x;
            xsT[sq * 4 + 1][srow] = v.y;
            xsT[sq * 4 + 2][srow] = v.z;
            xsT[sq * 4 + 3][srow] = v.w;
            xsT[(sq + 4) * 4 + 0][srow] = u.x;
            xsT[(sq + 4) * 4 + 1][srow] = u.y;
            xsT[(sq + 4) * 4 + 2][srow] = u.z;
            xsT[(sq + 4) * 4 + 3][srow] = u.w;
        }
        {
            const float4* wsrc = (const float4*)(W + k0 * 96);
            float4* wdst = (float4*)ws;
            wdst[tid] = wsrc[tid];
            wdst[tid + 256] = wsrc[tid + 256];
            wdst[tid + 512] = wsrc[tid + 512];
        }
        __syncthreads();
#pragma unroll
        for (int kk = 0; kk < 32; ++kk) {
            float4 xv = *(const float4*)&xsT[kk][r0];
            float wv[6];
            *(float2*)&wv[0] = *(const float2*)&ws[kk * 96 + c0];
            *(float2*)&wv[2] = *(const float2*)&ws[kk * 96 + c0 + 2];
            *(float2*)&wv[4] = *(const float2*)&ws[kk * 96 + c0 + 4];
            float xr[4] = {xv.x, xv.y, xv.z, xv.w};
#pragma unroll
            for (int i = 0; i < 4; ++i)
#pragma unroll
                for (int j = 0; j < 6; ++j) acc[i][j] += xr[i] * wv[j];
        }
        __syncthreads();
    }
#pragma unroll
    for (int i = 0; i < 4; ++i) {
        int grow = row0 + r0 + i;
        if (grow >= NN) break;
        __half2* yp = (__half2*)&Yh[(size_t)grow * HID + c0];
        yp[0] = __floats2half2_rn(acc[i][0], acc[i][1]);
        yp[1] = __floats2half2_rn(acc[i][2], acc[i][3]);
        yp[2] = __floats2half2_rn(acc[i][4], acc[i][5]);
    }
}

// ---------------- fused GCN aggregation + node-logit partial ----------------
// 32 threads per destination node; thread t owns features {t, t+32, t+64}.
template <int PHASE>
__global__ __launch_bounds__(256) void k_agg(const __half* __restrict__ Ah,
                                             const int2* __restrict__ ssrcw,
                                             const int* __restrict__ off,
                                             const float* __restrict__ dis,
                                             const float* __restrict__ bias,
                                             const float* __restrict__ Wn,
                                             const float* __restrict__ bn,
                                             float* __restrict__ out,
                                             float* __restrict__ nodeOut) {
    int gid = blockIdx.x * blockDim.x + threadIdx.x;
    int d = gid >> 5;
    int t = gid & 31;
    if (d >= NN) return;
    const int beg = off[d], end = off[d + 1];
    const float dd = dis[d];
    const __half* ad = Ah + (size_t)d * HID;
    float acc0 = __half2float(ad[t]) * dd * dd;
    float acc1 = __half2float(ad[t + 32]) * dd * dd;
    float acc2 = __half2float(ad[t + 64]) * dd * dd;
    int j = beg;
    // 8-wide unroll: batch descriptor loads, then 24 independent gathers
    for (; j + 7 < end; j += 8) {
        int2 e[8];
#pragma unroll
        for (int q = 0; q < 8; ++q) e[q] = ssrcw[j + q];
        float w[8];
        const __half* ap[8];
#pragma unroll
        for (int q = 0; q < 8; ++q) {
            w[q] = __int_as_float(e[q].y);
            ap[q] = Ah + (size_t)e[q].x * HID;
        }
        float g0[8], g1[8], g2[8];
#pragma unroll
        for (int q = 0; q < 8; ++q) {
            g0[q] = __half2float(ap[q][t]);
            g1[q] = __half2float(ap[q][t + 32]);
            g2[q] = __half2float(ap[q][t + 64]);
        }
#pragma unroll
        for (int q = 0; q < 8; ++q) {
            acc0 += g0[q] * w[q];
            acc1 += g1[q] * w[q];
            acc2 += g2[q] * w[q];
        }
    }
    for (; j < end; ++j) {
        int2 e0 = ssrcw[j];
        float w0 = __int_as_float(e0.y);
        const __half* a0 = Ah + (size_t)e0.x * HID;
        acc0 += __half2float(a0[t]) * w0;
        acc1 += __half2float(a0[t + 32]) * w0;
        acc2 += __half2float(a0[t + 64]) * w0;
    }
    float h0 = fmaxf(acc0 + bias[t], 0.f);
    float h1v = fmaxf(acc1 + bias[t + 32], 0.f);
    float h2v = fmaxf(acc2 + bias[t + 64], 0.f);
    float* o = out + (size_t)d * HID;
    o[t] = h0; o[t + 32] = h1v; o[t + 64] = h2v;

    const int woff = (PHASE == 1) ? 0 : 96;
    float partial = h0 * Wn[woff + t] + h1v * Wn[woff + t + 32] + h2v * Wn[woff + t + 64];
#pragma unroll
    for (int m = 16; m; m >>= 1) partial += __shfl_down(partial, m, 32);
    if (t == 0) {
        if (PHASE == 1) nodeOut[d] = partial + bn[0];
        else            nodeOut[d] += partial;
    }
}

// ---------------- graph pooling + graph head ----------------
// 768 threads: 4 node-ways x 192 features
__global__ __launch_bounds__(768) void k_pool(const float* __restrict__ h1,
                                              const float* __restrict__ h2,
                                              const int* __restrict__ batch,
                                              const float* __restrict__ Wg,
                                              const float* __restrict__ bg,
                                              float* __restrict__ out) {
    int g = blockIdx.x;
    int tid = threadIdx.x;       // 0..767
    int way = tid / 192;         // 0..3
    int f = tid - way * 192;     // 0..191

    int lo = 0, hi = NN;
    while (lo < hi) { int mid = (lo + hi) >> 1; if (batch[mid] < g) lo = mid + 1; else hi = mid; }
    int start = lo;
    hi = NN;
    while (lo < hi) { int mid = (lo + hi) >> 1; if (batch[mid] < g + 1) lo = mid + 1; else hi = mid; }
    int end = lo;

    const float* hsrc = (f < HID) ? h1 : h2;
    int ff = (f < HID) ? f : f - HID;
    float sum = 0.f, mx = 0.f;  // h >= 0 post-relu
    for (int n = start + way; n < end; n += 4) {
        float v = hsrc[(size_t)n * HID + ff];
        sum += v;
        mx = fmaxf(mx, v);
    }
    __shared__ float rsum[4][192];
    __shared__ float rmax[4][192];
    rsum[way][f] = sum;
    rmax[way][f] = mx;
    __syncthreads();
    if (way == 0) {
        sum = rsum[0][f] + rsum[1][f] + rsum[2][f] + rsum[3][f];
        mx = fmaxf(fmaxf(rmax[0][f], rmax[1][f]), fmaxf(rmax[2][f], rmax[3][f]));
        float cnt = (float)(end - start);
        float mean = sum / fmaxf(cnt, 1.0f);
        rsum[0][f] = mean * Wg[f] + mx * Wg[192 + f];
    }
    __syncthreads();
    if (tid < 64) {
        float acc = rsum[0][tid] + rsum[0][tid + 64] + rsum[0][tid + 128];
#pragma unroll
        for (int m = 32; m; m >>= 1) acc += __shfl_down(acc, m, 64);
        if (tid == 0) out[g] = acc + bg[0];
    }
}

extern "C" void kernel_launch(void* const* d_in, const int* in_sizes, int n_in,
                              void* d_out, int out_size, void* d_ws, size_t ws_size,
                              hipStream_t stream) {
    const float* x    = (const float*)d_in[0];
    const int*   ei   = (const int*)d_in[1];
    const int*   srcp = ei;
    const int*   dstp = ei + NE;
    const int*   batch = (const int*)d_in[2];
    const float* W1 = (const float*)d_in[3];
    const float* b1 = (const float*)d_in[4];
    const float* W2 = (const float*)d_in[5];
    const float* b2 = (const float*)d_in[6];
    const float* Wn = (const float*)d_in[7];
    const float* bn = (const float*)d_in[8];
    const float* Wg = (const float*)d_in[9];
    const float* bg = (const float*)d_in[10];
    float* out = (float*)d_out;

    char* p = (char*)d_ws;
    auto alloc = [&](size_t bytes) {
        char* r = p;
        p += (bytes + 255) & ~(size_t)255;
        return (void*)r;
    };
    float*    dis   = (float*)alloc(NN * 4);
    int*      off   = (int*)alloc((NN + 1) * 4);
    int*      bcur  = (int*)alloc(NB * 4);
    int*      bsum  = (int*)alloc(128 * 4);
    unsigned* tmp   = (unsigned*)alloc((size_t)NE * 4);
    int2*     ssrcw = (int2*)alloc((size_t)NE * 8);
    __half*   Ah    = (__half*)alloc((size_t)NN * HID * 2);
    float*    H1    = (float*)alloc((size_t)NN * HID * 4);
    float*    H2    = (float*)alloc((size_t)NN * HID * 4);

    const int TPB = 256;
    const int nScan = NN + 1;
    const int nbScan = (nScan + 1023) / 1024;    // 98

    // CSR build
    k_zero<<<(NN + TPB) / TPB, TPB, 0, stream>>>(off, bcur);
    k_hist<<<(NE + TPB - 1) / TPB, TPB, 0, stream>>>(dstp, off);
    k_scan1<<<nbScan, 256, 0, stream>>>(off, bsum, nScan);
    k_scan2<<<1, 128, 0, stream>>>(bsum, nbScan);
    k_scan3<<<nbScan, 256, 0, stream>>>(off, bsum, nScan);
    k_dis<<<(NN + TPB - 1) / TPB, TPB, 0, stream>>>(off, dis);
    k_bin<<<(NE + TPB - 1) / TPB, TPB, 0, stream>>>(srcp, dstp, off, bcur, tmp);
    k_csr<<<NB, 256, 0, stream>>>(tmp, off, dis, ssrcw);

    const int aggThreads = NN * 32;
    float* nodeOut = out + NG;

    // conv1: Ah = fp16(x@W1) ; H1 = relu(agg(Ah) + b1) ; nodeOut = bn + H1.Wn[:96]
    k_gemm<INC><<<(NN + 63) / 64, 256, 0, stream>>>(x, W1, Ah);
    k_agg<1><<<(aggThreads + TPB - 1) / TPB, TPB, 0, stream>>>(Ah, ssrcw, off, dis, b1, Wn, bn, H1, nodeOut);

    // conv2: Ah = fp16(H1@W2) ; H2 = relu(agg(Ah) + b2) ; nodeOut += H2.Wn[96:]
    k_gemm<HID><<<(NN + 63) / 64, 256, 0, stream>>>(H1, W2, Ah);
    k_agg<2><<<(aggThreads + TPB - 1) / TPB, TPB, 0, stream>>>(Ah, ssrcw, off, dis, b2, Wn, bn, H2, nodeOut);

    // pooling + graph head
    k_pool<<<NG, 768, 0, stream>>>(H1, H2, batch, Wg, bg, out);
}

// Round 7
// 430.527 us; speedup vs baseline: 1.6439x; 1.6439x over previous
//
#include <hip/hip_runtime.h>
#include <hip/hip_fp16.h>

#define NN 100000      // nodes
#define NE 1600000     // edges
#define INC 128        // in channels
#define HID 96         // hidden
#define NG 512         // graphs

// ---------------- CSR build: histogram, scan, reorder ----------------
__global__ void k_zero(int* __restrict__ off, int* __restrict__ cur) {
    int i = blockIdx.x * blockDim.x + threadIdx.x;
    if (i < NN + 1) off[i] = 0;
    if (i < NN) cur[i] = 0;
}

__global__ void k_hist(const int* __restrict__ dst, int* __restrict__ off) {
    int e = blockIdx.x * blockDim.x + threadIdx.x;
    if (e < NE) atomicAdd(&off[dst[e] + 1], 1);
}

// 3-phase scan: blockwise scan (1024 elems/block) -> scan block sums -> add
__global__ __launch_bounds__(256) void k_scan1(int* __restrict__ a, int* __restrict__ bsum, int n) {
    __shared__ int s[256];
    int base = blockIdx.x * 1024 + threadIdx.x * 4;
    int v0 = (base + 0 < n) ? a[base + 0] : 0;
    int v1 = (base + 1 < n) ? a[base + 1] : 0;
    int v2 = (base + 2 < n) ? a[base + 2] : 0;
    int v3 = (base + 3 < n) ? a[base + 3] : 0;
    v1 += v0; v2 += v1; v3 += v2;
    s[threadIdx.x] = v3;
    __syncthreads();
    for (int ofs = 1; ofs < 256; ofs <<= 1) {
        int t = (threadIdx.x >= ofs) ? s[threadIdx.x - ofs] : 0;
        __syncthreads();
        s[threadIdx.x] += t;
        __syncthreads();
    }
    int pre = (threadIdx.x > 0) ? s[threadIdx.x - 1] : 0;
    v0 += pre; v1 += pre; v2 += pre; v3 += pre;
    if (base + 0 < n) a[base + 0] = v0;
    if (base + 1 < n) a[base + 1] = v1;
    if (base + 2 < n) a[base + 2] = v2;
    if (base + 3 < n) a[base + 3] = v3;
    if (threadIdx.x == 255) bsum[blockIdx.x] = s[255];
}

__global__ __launch_bounds__(128) void k_scan2(int* __restrict__ bsum, int nb) {
    __shared__ int s[128];
    int v = (threadIdx.x < nb) ? bsum[threadIdx.x] : 0;
    s[threadIdx.x] = v;
    __syncthreads();
    for (int ofs = 1; ofs < 128; ofs <<= 1) {
        int t = (threadIdx.x >= ofs) ? s[threadIdx.x - ofs] : 0;
        __syncthreads();
        s[threadIdx.x] += t;
        __syncthreads();
    }
    if (threadIdx.x < nb) bsum[threadIdx.x] = s[threadIdx.x];  // inclusive
}

__global__ __launch_bounds__(256) void k_scan3(int* __restrict__ a, const int* __restrict__ bsum, int n) {
    int b = blockIdx.x;
    if (b == 0) return;
    int add = bsum[b - 1];
    int base = b * 1024 + threadIdx.x * 4;
#pragma unroll
    for (int j = 0; j < 4; ++j) {
        int idx = base + j;
        if (idx < n) a[idx] += add;
    }
}

// dis[i] = rsqrt(deg_in + selfloop)
__global__ void k_dis(const int* __restrict__ off, float* __restrict__ dis) {
    int i = blockIdx.x * blockDim.x + threadIdx.x;
    if (i < NN) dis[i] = rsqrtf((float)(off[i + 1] - off[i] + 1));
}

// scatter src into CSR order (4B payload; w recomputed in agg from dis)
__global__ void k_reorder(const int* __restrict__ src, const int* __restrict__ dst,
                          const int* __restrict__ off, int* __restrict__ cur,
                          int* __restrict__ ssrc) {
    int e = blockIdx.x * blockDim.x + threadIdx.x;
    if (e >= NE) return;
    int s = src[e], d = dst[e];
    int p = off[d] + atomicAdd(&cur[d], 1);
    ssrc[p] = s;
}

// ---------------- register-tiled GEMM: Yh[N,96] (fp16) = X[N,K] @ W[K,96] ----------------
template <int K>
__global__ __launch_bounds__(256) void k_gemm(const float* __restrict__ X,
                                              const float* __restrict__ W,
                                              __half* __restrict__ Yh) {
    __shared__ float xsT[32][64];   // X tile, transposed
    __shared__ float ws[32 * 96];   // W tile (rows contiguous)
    const int tid = threadIdx.x;
    const int row0 = blockIdx.x * 64;
    const int rg = tid >> 4;        // 0..15
    const int cg = tid & 15;        // 0..15
    const int r0 = rg * 4, c0 = cg * 6;
    float acc[4][6] = {};

    const int srow = tid & 63;      // staging row
    const int sq = tid >> 6;        // 0..3

    for (int k0 = 0; k0 < K; k0 += 32) {
        {
            int grow = row0 + srow;
            float4 v = make_float4(0.f, 0.f, 0.f, 0.f);
            float4 u = make_float4(0.f, 0.f, 0.f, 0.f);
            if (grow < NN) {
                v = *(const float4*)&X[(size_t)grow * K + k0 + sq * 4];
                u = *(const float4*)&X[(size_t)grow * K + k0 + (sq + 4) * 4];
            }
            xsT[sq * 4 + 0][srow] = v.x;
            xsT[sq * 4 + 1][srow] = v.y;
            xsT[sq * 4 + 2][srow] = v.z;
            xsT[sq * 4 + 3][srow] = v.w;
            xsT[(sq + 4) * 4 + 0][srow] = u.x;
            xsT[(sq + 4) * 4 + 1][srow] = u.y;
            xsT[(sq + 4) * 4 + 2][srow] = u.z;
            xsT[(sq + 4) * 4 + 3][srow] = u.w;
        }
        {
            const float4* wsrc = (const float4*)(W + k0 * 96);
            float4* wdst = (float4*)ws;
            wdst[tid] = wsrc[tid];
            wdst[tid + 256] = wsrc[tid + 256];
            wdst[tid + 512] = wsrc[tid + 512];
        }
        __syncthreads();
#pragma unroll
        for (int kk = 0; kk < 32; ++kk) {
            float4 xv = *(const float4*)&xsT[kk][r0];
            float wv[6];
            *(float2*)&wv[0] = *(const float2*)&ws[kk * 96 + c0];
            *(float2*)&wv[2] = *(const float2*)&ws[kk * 96 + c0 + 2];
            *(float2*)&wv[4] = *(const float2*)&ws[kk * 96 + c0 + 4];
            float xr[4] = {xv.x, xv.y, xv.z, xv.w};
#pragma unroll
            for (int i = 0; i < 4; ++i)
#pragma unroll
                for (int j = 0; j < 6; ++j) acc[i][j] += xr[i] * wv[j];
        }
        __syncthreads();
    }
#pragma unroll
    for (int i = 0; i < 4; ++i) {
        int grow = row0 + r0 + i;
        if (grow >= NN) break;
        __half2* yp = (__half2*)&Yh[(size_t)grow * HID + c0];
        yp[0] = __floats2half2_rn(acc[i][0], acc[i][1]);
        yp[1] = __floats2half2_rn(acc[i][2], acc[i][3]);
        yp[2] = __floats2half2_rn(acc[i][4], acc[i][5]);
    }
}

// ---------------- fused GCN aggregation + node-logit partial ----------------
// 32 threads per destination node; thread t owns features {t, t+32, t+64}.
// PHASE 1: nodeOut[d] = bn + h1 . Wn[0:96]      PHASE 2: nodeOut[d] += h2 . Wn[96:192]
template <int PHASE>
__global__ __launch_bounds__(256) void k_agg(const __half* __restrict__ Ah,
                                             const int* __restrict__ ssrc,
                                             const int* __restrict__ off,
                                             const float* __restrict__ dis,
                                             const float* __restrict__ bias,
                                             const float* __restrict__ Wn,
                                             const float* __restrict__ bn,
                                             float* __restrict__ out,
                                             float* __restrict__ nodeOut) {
    int gid = blockIdx.x * blockDim.x + threadIdx.x;
    int d = gid >> 5;
    int t = gid & 31;
    if (d >= NN) return;
    const int beg = off[d], end = off[d + 1];
    const float dd = dis[d];
    const __half* ad = Ah + (size_t)d * HID;
    float acc0 = __half2float(ad[t]) * dd * dd;
    float acc1 = __half2float(ad[t + 32]) * dd * dd;
    float acc2 = __half2float(ad[t + 64]) * dd * dd;
    int j = beg;
    // 8-wide unroll: batch descriptor + dis loads, then 24 independent gathers
    for (; j + 7 < end; j += 8) {
        int s[8];
#pragma unroll
        for (int q = 0; q < 8; ++q) s[q] = ssrc[j + q];
        float w[8];
        const __half* ap[8];
#pragma unroll
        for (int q = 0; q < 8; ++q) {
            w[q] = dis[s[q]] * dd;
            ap[q] = Ah + (size_t)s[q] * HID;
        }
        float g0[8], g1[8], g2[8];
#pragma unroll
        for (int q = 0; q < 8; ++q) {
            g0[q] = __half2float(ap[q][t]);
            g1[q] = __half2float(ap[q][t + 32]);
            g2[q] = __half2float(ap[q][t + 64]);
        }
#pragma unroll
        for (int q = 0; q < 8; ++q) {
            acc0 += g0[q] * w[q];
            acc1 += g1[q] * w[q];
            acc2 += g2[q] * w[q];
        }
    }
    for (; j < end; ++j) {
        int s0 = ssrc[j];
        float w0 = dis[s0] * dd;
        const __half* a0 = Ah + (size_t)s0 * HID;
        acc0 += __half2float(a0[t]) * w0;
        acc1 += __half2float(a0[t + 32]) * w0;
        acc2 += __half2float(a0[t + 64]) * w0;
    }
    float h0 = fmaxf(acc0 + bias[t], 0.f);
    float h1v = fmaxf(acc1 + bias[t + 32], 0.f);
    float h2v = fmaxf(acc2 + bias[t + 64], 0.f);
    float* o = out + (size_t)d * HID;
    o[t] = h0; o[t + 32] = h1v; o[t + 64] = h2v;

    const int woff = (PHASE == 1) ? 0 : 96;
    float partial = h0 * Wn[woff + t] + h1v * Wn[woff + t + 32] + h2v * Wn[woff + t + 64];
#pragma unroll
    for (int m = 16; m; m >>= 1) partial += __shfl_down(partial, m, 32);
    if (t == 0) {
        if (PHASE == 1) nodeOut[d] = partial + bn[0];
        else            nodeOut[d] += partial;
    }
}

// ---------------- graph pooling + graph head ----------------
// 768 threads: 4 node-ways x 192 features
__global__ __launch_bounds__(768) void k_pool(const float* __restrict__ h1,
                                              const float* __restrict__ h2,
                                              const int* __restrict__ batch,
                                              const float* __restrict__ Wg,
                                              const float* __restrict__ bg,
                                              float* __restrict__ out) {
    int g = blockIdx.x;
    int tid = threadIdx.x;       // 0..767
    int way = tid / 192;         // 0..3
    int f = tid - way * 192;     // 0..191

    int lo = 0, hi = NN;
    while (lo < hi) { int mid = (lo + hi) >> 1; if (batch[mid] < g) lo = mid + 1; else hi = mid; }
    int start = lo;
    hi = NN;
    while (lo < hi) { int mid = (lo + hi) >> 1; if (batch[mid] < g + 1) lo = mid + 1; else hi = mid; }
    int end = lo;

    const float* hsrc = (f < HID) ? h1 : h2;
    int ff = (f < HID) ? f : f - HID;
    float sum = 0.f, mx = 0.f;  // h >= 0 post-relu
    for (int n = start + way; n < end; n += 4) {
        float v = hsrc[(size_t)n * HID + ff];
        sum += v;
        mx = fmaxf(mx, v);
    }
    __shared__ float rsum[4][192];
    __shared__ float rmax[4][192];
    rsum[way][f] = sum;
    rmax[way][f] = mx;
    __syncthreads();
    if (way == 0) {
        sum = rsum[0][f] + rsum[1][f] + rsum[2][f] + rsum[3][f];
        mx = fmaxf(fmaxf(rmax[0][f], rmax[1][f]), fmaxf(rmax[2][f], rmax[3][f]));
        float cnt = (float)(end - start);
        float mean = sum / fmaxf(cnt, 1.0f);
        rsum[0][f] = mean * Wg[f] + mx * Wg[192 + f];
    }
    __syncthreads();
    if (tid < 64) {
        float acc = rsum[0][tid] + rsum[0][tid + 64] + rsum[0][tid + 128];
#pragma unroll
        for (int m = 32; m; m >>= 1) acc += __shfl_down(acc, m, 64);
        if (tid == 0) out[g] = acc + bg[0];
    }
}

extern "C" void kernel_launch(void* const* d_in, const int* in_sizes, int n_in,
                              void* d_out, int out_size, void* d_ws, size_t ws_size,
                              hipStream_t stream) {
    const float* x    = (const float*)d_in[0];
    const int*   ei   = (const int*)d_in[1];
    const int*   srcp = ei;
    const int*   dstp = ei + NE;
    const int*   batch = (const int*)d_in[2];
    const float* W1 = (const float*)d_in[3];
    const float* b1 = (const float*)d_in[4];
    const float* W2 = (const float*)d_in[5];
    const float* b2 = (const float*)d_in[6];
    const float* Wn = (const float*)d_in[7];
    const float* bn = (const float*)d_in[8];
    const float* Wg = (const float*)d_in[9];
    const float* bg = (const float*)d_in[10];
    float* out = (float*)d_out;

    char* p = (char*)d_ws;
    auto alloc = [&](size_t bytes) {
        char* r = p;
        p += (bytes + 255) & ~(size_t)255;
        return (void*)r;
    };
    float*  dis   = (float*)alloc(NN * 4);
    int*    off   = (int*)alloc((NN + 1) * 4);
    int*    cur   = (int*)alloc(NN * 4);
    int*    bsum  = (int*)alloc(128 * 4);
    int*    ssrc  = (int*)alloc((size_t)NE * 4);
    __half* Ah    = (__half*)alloc((size_t)NN * HID * 2);
    float*  H1    = (float*)alloc((size_t)NN * HID * 4);
    float*  H2    = (float*)alloc((size_t)NN * HID * 4);

    const int TPB = 256;
    const int nScan = NN + 1;
    const int nbScan = (nScan + 1023) / 1024;    // 98

    // CSR build
    k_zero<<<(NN + TPB) / TPB, TPB, 0, stream>>>(off, cur);
    k_hist<<<(NE + TPB - 1) / TPB, TPB, 0, stream>>>(dstp, off);
    k_scan1<<<nbScan, 256, 0, stream>>>(off, bsum, nScan);
    k_scan2<<<1, 128, 0, stream>>>(bsum, nbScan);
    k_scan3<<<nbScan, 256, 0, stream>>>(off, bsum, nScan);
    k_dis<<<(NN + TPB - 1) / TPB, TPB, 0, stream>>>(off, dis);
    k_reorder<<<(NE + TPB - 1) / TPB, TPB, 0, stream>>>(srcp, dstp, off, cur, ssrc);

    const int aggThreads = NN * 32;
    float* nodeOut = out + NG;

    // conv1: Ah = fp16(x@W1) ; H1 = relu(agg(Ah) + b1) ; nodeOut = bn + H1.Wn[:96]
    k_gemm<INC><<<(NN + 63) / 64, 256, 0, stream>>>(x, W1, Ah);
    k_agg<1><<<(aggThreads + TPB - 1) / TPB, TPB, 0, stream>>>(Ah, ssrc, off, dis, b1, Wn, bn, H1, nodeOut);

    // conv2: Ah = fp16(H1@W2) ; H2 = relu(agg(Ah) + b2) ; nodeOut += H2.Wn[96:]
    k_gemm<HID><<<(NN + 63) / 64, 256, 0, stream>>>(H1, W2, Ah);
    k_agg<2><<<(aggThreads + TPB - 1) / TPB, TPB, 0, stream>>>(Ah, ssrc, off, dis, b2, Wn, bn, H2, nodeOut);

    // pooling + graph head
    k_pool<<<NG, 768, 0, stream>>>(H1, H2, batch, Wg, bg, out);
}

// Round 8
// 362.859 us; speedup vs baseline: 1.9505x; 1.1865x over previous
//
#include <hip/hip_runtime.h>
#include <hip/hip_fp16.h>

#define NN 100000      // nodes
#define NE 1600000     // edges
#define INC 128        // in channels
#define HID 96         // hidden
#define NG 512         // graphs

#define GEMM1_BLOCKS 1563        // ceil(NN/64)
#define REORDER_BLOCKS 6250      // ceil(NE/256)

// ---------------- CSR build: histogram, scan ----------------
__global__ void k_zero(int* __restrict__ off, int* __restrict__ cur) {
    int i = blockIdx.x * blockDim.x + threadIdx.x;
    if (i < NN + 1) off[i] = 0;
    if (i < NN) cur[i] = 0;
}

__global__ void k_hist(const int* __restrict__ dst, int* __restrict__ off) {
    int e = blockIdx.x * blockDim.x + threadIdx.x;
    if (e < NE) atomicAdd(&off[dst[e] + 1], 1);
}

// 3-phase scan: blockwise scan (1024 elems/block) -> scan block sums -> add
__global__ __launch_bounds__(256) void k_scan1(int* __restrict__ a, int* __restrict__ bsum, int n) {
    __shared__ int s[256];
    int base = blockIdx.x * 1024 + threadIdx.x * 4;
    int v0 = (base + 0 < n) ? a[base + 0] : 0;
    int v1 = (base + 1 < n) ? a[base + 1] : 0;
    int v2 = (base + 2 < n) ? a[base + 2] : 0;
    int v3 = (base + 3 < n) ? a[base + 3] : 0;
    v1 += v0; v2 += v1; v3 += v2;
    s[threadIdx.x] = v3;
    __syncthreads();
    for (int ofs = 1; ofs < 256; ofs <<= 1) {
        int t = (threadIdx.x >= ofs) ? s[threadIdx.x - ofs] : 0;
        __syncthreads();
        s[threadIdx.x] += t;
        __syncthreads();
    }
    int pre = (threadIdx.x > 0) ? s[threadIdx.x - 1] : 0;
    v0 += pre; v1 += pre; v2 += pre; v3 += pre;
    if (base + 0 < n) a[base + 0] = v0;
    if (base + 1 < n) a[base + 1] = v1;
    if (base + 2 < n) a[base + 2] = v2;
    if (base + 3 < n) a[base + 3] = v3;
    if (threadIdx.x == 255) bsum[blockIdx.x] = s[255];
}

__global__ __launch_bounds__(128) void k_scan2(int* __restrict__ bsum, int nb) {
    __shared__ int s[128];
    int v = (threadIdx.x < nb) ? bsum[threadIdx.x] : 0;
    s[threadIdx.x] = v;
    __syncthreads();
    for (int ofs = 1; ofs < 128; ofs <<= 1) {
        int t = (threadIdx.x >= ofs) ? s[threadIdx.x - ofs] : 0;
        __syncthreads();
        s[threadIdx.x] += t;
        __syncthreads();
    }
    if (threadIdx.x < nb) bsum[threadIdx.x] = s[threadIdx.x];  // inclusive
}

__global__ __launch_bounds__(256) void k_scan3(int* __restrict__ a, const int* __restrict__ bsum, int n) {
    int b = blockIdx.x;
    if (b == 0) return;
    int add = bsum[b - 1];
    int base = b * 1024 + threadIdx.x * 4;
#pragma unroll
    for (int j = 0; j < 4; ++j) {
        int idx = base + j;
        if (idx < n) a[idx] += add;
    }
}

// dis[i] = rsqrt(deg_in + selfloop)
__global__ void k_dis(const int* __restrict__ off, float* __restrict__ dis) {
    int i = blockIdx.x * blockDim.x + threadIdx.x;
    if (i < NN) dis[i] = rsqrtf((float)(off[i + 1] - off[i] + 1));
}

// ---------------- FUSED: gemm1 (compute-bound) ∥ reorder (write-bound) ----------------
// blocks [0, GEMM1_BLOCKS): Yh[N,96] = fp16(X[N,128] @ W1) tile body
// blocks [GEMM1_BLOCKS, +REORDER_BLOCKS): scatter {src, dis[s]*dis[d]} into CSR order
__global__ __launch_bounds__(256) void k_gemm1_reorder(
        const float* __restrict__ X, const float* __restrict__ W, __half* __restrict__ Yh,
        const int* __restrict__ src, const int* __restrict__ dst,
        const int* __restrict__ off, int* __restrict__ cur,
        const float* __restrict__ dis, int2* __restrict__ ssrcw) {
    __shared__ float xsT[32][64];   // X tile, transposed
    __shared__ float ws[32 * 96];   // W tile
    const int tid = threadIdx.x;

    if (blockIdx.x >= GEMM1_BLOCKS) {
        // -------- reorder body --------
        int e = (blockIdx.x - GEMM1_BLOCKS) * 256 + tid;
        if (e < NE) {
            int s = src[e], d = dst[e];
            int p = off[d] + atomicAdd(&cur[d], 1);
            float w = dis[s] * dis[d];
            ssrcw[p] = make_int2(s, __float_as_int(w));
        }
        return;
    }

    // -------- gemm body (K = INC = 128) --------
    const int row0 = blockIdx.x * 64;
    const int rg = tid >> 4;        // 0..15
    const int cg = tid & 15;        // 0..15
    const int r0 = rg * 4, c0 = cg * 6;
    float acc[4][6] = {};
    const int srow = tid & 63;      // staging row
    const int sq = tid >> 6;        // 0..3

    for (int k0 = 0; k0 < INC; k0 += 32) {
        {
            int grow = row0 + srow;
            float4 v = make_float4(0.f, 0.f, 0.f, 0.f);
            float4 u = make_float4(0.f, 0.f, 0.f, 0.f);
            if (grow < NN) {
                v = *(const float4*)&X[(size_t)grow * INC + k0 + sq * 4];
                u = *(const float4*)&X[(size_t)grow * INC + k0 + (sq + 4) * 4];
            }
            xsT[sq * 4 + 0][srow] = v.x;
            xsT[sq * 4 + 1][srow] = v.y;
            xsT[sq * 4 + 2][srow] = v.z;
            xsT[sq * 4 + 3][srow] = v.w;
            xsT[(sq + 4) * 4 + 0][srow] = u.x;
            xsT[(sq + 4) * 4 + 1][srow] = u.y;
            xsT[(sq + 4) * 4 + 2][srow] = u.z;
            xsT[(sq + 4) * 4 + 3][srow] = u.w;
        }
        {
            const float4* wsrc = (const float4*)(W + k0 * 96);
            float4* wdst = (float4*)ws;
            wdst[tid] = wsrc[tid];
            wdst[tid + 256] = wsrc[tid + 256];
            wdst[tid + 512] = wsrc[tid + 512];
        }
        __syncthreads();
#pragma unroll
        for (int kk = 0; kk < 32; ++kk) {
            float4 xv = *(const float4*)&xsT[kk][r0];
            float wv[6];
            *(float2*)&wv[0] = *(const float2*)&ws[kk * 96 + c0];
            *(float2*)&wv[2] = *(const float2*)&ws[kk * 96 + c0 + 2];
            *(float2*)&wv[4] = *(const float2*)&ws[kk * 96 + c0 + 4];
            float xr[4] = {xv.x, xv.y, xv.z, xv.w};
#pragma unroll
            for (int i = 0; i < 4; ++i)
#pragma unroll
                for (int j = 0; j < 6; ++j) acc[i][j] += xr[i] * wv[j];
        }
        __syncthreads();
    }
#pragma unroll
    for (int i = 0; i < 4; ++i) {
        int grow = row0 + r0 + i;
        if (grow >= NN) break;
        __half2* yp = (__half2*)&Yh[(size_t)grow * HID + c0];
        yp[0] = __floats2half2_rn(acc[i][0], acc[i][1]);
        yp[1] = __floats2half2_rn(acc[i][2], acc[i][3]);
        yp[2] = __floats2half2_rn(acc[i][4], acc[i][5]);
    }
}

// ---------------- standalone GEMM (conv2): Yh[N,96] = fp16(X[N,96] @ W[96,96]) ----------------
template <int K>
__global__ __launch_bounds__(256) void k_gemm(const float* __restrict__ X,
                                              const float* __restrict__ W,
                                              __half* __restrict__ Yh) {
    __shared__ float xsT[32][64];
    __shared__ float ws[32 * 96];
    const int tid = threadIdx.x;
    const int row0 = blockIdx.x * 64;
    const int rg = tid >> 4;
    const int cg = tid & 15;
    const int r0 = rg * 4, c0 = cg * 6;
    float acc[4][6] = {};
    const int srow = tid & 63;
    const int sq = tid >> 6;

    for (int k0 = 0; k0 < K; k0 += 32) {
        {
            int grow = row0 + srow;
            float4 v = make_float4(0.f, 0.f, 0.f, 0.f);
            float4 u = make_float4(0.f, 0.f, 0.f, 0.f);
            if (grow < NN) {
                v = *(const float4*)&X[(size_t)grow * K + k0 + sq * 4];
                u = *(const float4*)&X[(size_t)grow * K + k0 + (sq + 4) * 4];
            }
            xsT[sq * 4 + 0][srow] = v.x;
            xsT[sq * 4 + 1][srow] = v.y;
            xsT[sq * 4 + 2][srow] = v.z;
            xsT[sq * 4 + 3][srow] = v.w;
            xsT[(sq + 4) * 4 + 0][srow] = u.x;
            xsT[(sq + 4) * 4 + 1][srow] = u.y;
            xsT[(sq + 4) * 4 + 2][srow] = u.z;
            xsT[(sq + 4) * 4 + 3][srow] = u.w;
        }
        {
            const float4* wsrc = (const float4*)(W + k0 * 96);
            float4* wdst = (float4*)ws;
            wdst[tid] = wsrc[tid];
            wdst[tid + 256] = wsrc[tid + 256];
            wdst[tid + 512] = wsrc[tid + 512];
        }
        __syncthreads();
#pragma unroll
        for (int kk = 0; kk < 32; ++kk) {
            float4 xv = *(const float4*)&xsT[kk][r0];
            float wv[6];
            *(float2*)&wv[0] = *(const float2*)&ws[kk * 96 + c0];
            *(float2*)&wv[2] = *(const float2*)&ws[kk * 96 + c0 + 2];
            *(float2*)&wv[4] = *(const float2*)&ws[kk * 96 + c0 + 4];
            float xr[4] = {xv.x, xv.y, xv.z, xv.w};
#pragma unroll
            for (int i = 0; i < 4; ++i)
#pragma unroll
                for (int j = 0; j < 6; ++j) acc[i][j] += xr[i] * wv[j];
        }
        __syncthreads();
    }
#pragma unroll
    for (int i = 0; i < 4; ++i) {
        int grow = row0 + r0 + i;
        if (grow >= NN) break;
        __half2* yp = (__half2*)&Yh[(size_t)grow * HID + c0];
        yp[0] = __floats2half2_rn(acc[i][0], acc[i][1]);
        yp[1] = __floats2half2_rn(acc[i][2], acc[i][3]);
        yp[2] = __floats2half2_rn(acc[i][4], acc[i][5]);
    }
}

// ---------------- fused GCN aggregation + node-logit partial ----------------
// 32 threads per destination node; thread t owns features {t, t+32, t+64}.
// PHASE 1: nodeOut[d] = bn + h1 . Wn[0:96]      PHASE 2: nodeOut[d] += h2 . Wn[96:192]
template <int PHASE>
__global__ __launch_bounds__(256) void k_agg(const __half* __restrict__ Ah,
                                             const int2* __restrict__ ssrcw,
                                             const int* __restrict__ off,
                                             const float* __restrict__ dis,
                                             const float* __restrict__ bias,
                                             const float* __restrict__ Wn,
                                             const float* __restrict__ bn,
                                             float* __restrict__ out,
                                             float* __restrict__ nodeOut) {
    int gid = blockIdx.x * blockDim.x + threadIdx.x;
    int d = gid >> 5;
    int t = gid & 31;
    if (d >= NN) return;
    const int beg = off[d], end = off[d + 1];
    const float dd = dis[d];
    const __half* ad = Ah + (size_t)d * HID;
    float acc0 = __half2float(ad[t]) * dd * dd;
    float acc1 = __half2float(ad[t + 32]) * dd * dd;
    float acc2 = __half2float(ad[t + 64]) * dd * dd;
    int j = beg;
    // 8-wide unroll: batch descriptor loads, then 24 independent gathers
    for (; j + 7 < end; j += 8) {
        int2 e[8];
#pragma unroll
        for (int q = 0; q < 8; ++q) e[q] = ssrcw[j + q];
        float w[8];
        const __half* ap[8];
#pragma unroll
        for (int q = 0; q < 8; ++q) {
            w[q] = __int_as_float(e[q].y);
            ap[q] = Ah + (size_t)e[q].x * HID;
        }
        float g0[8], g1[8], g2[8];
#pragma unroll
        for (int q = 0; q < 8; ++q) {
            g0[q] = __half2float(ap[q][t]);
            g1[q] = __half2float(ap[q][t + 32]);
            g2[q] = __half2float(ap[q][t + 64]);
        }
#pragma unroll
        for (int q = 0; q < 8; ++q) {
            acc0 += g0[q] * w[q];
            acc1 += g1[q] * w[q];
            acc2 += g2[q] * w[q];
        }
    }
    for (; j < end; ++j) {
        int2 e0 = ssrcw[j];
        float w0 = __int_as_float(e0.y);
        const __half* a0 = Ah + (size_t)e0.x * HID;
        acc0 += __half2float(a0[t]) * w0;
        acc1 += __half2float(a0[t + 32]) * w0;
        acc2 += __half2float(a0[t + 64]) * w0;
    }
    float h0 = fmaxf(acc0 + bias[t], 0.f);
    float h1v = fmaxf(acc1 + bias[t + 32], 0.f);
    float h2v = fmaxf(acc2 + bias[t + 64], 0.f);
    float* o = out + (size_t)d * HID;
    o[t] = h0; o[t + 32] = h1v; o[t + 64] = h2v;

    const int woff = (PHASE == 1) ? 0 : 96;
    float partial = h0 * Wn[woff + t] + h1v * Wn[woff + t + 32] + h2v * Wn[woff + t + 64];
#pragma unroll
    for (int m = 16; m; m >>= 1) partial += __shfl_down(partial, m, 32);
    if (t == 0) {
        if (PHASE == 1) nodeOut[d] = partial + bn[0];
        else            nodeOut[d] += partial;
    }
}

// ---------------- graph pooling + graph head ----------------
// 768 threads: 4 node-ways x 192 features
__global__ __launch_bounds__(768) void k_pool(const float* __restrict__ h1,
                                              const float* __restrict__ h2,
                                              const int* __restrict__ batch,
                                              const float* __restrict__ Wg,
                                              const float* __restrict__ bg,
                                              float* __restrict__ out) {
    int g = blockIdx.x;
    int tid = threadIdx.x;       // 0..767
    int way = tid / 192;         // 0..3
    int f = tid - way * 192;     // 0..191

    int lo = 0, hi = NN;
    while (lo < hi) { int mid = (lo + hi) >> 1; if (batch[mid] < g) lo = mid + 1; else hi = mid; }
    int start = lo;
    hi = NN;
    while (lo < hi) { int mid = (lo + hi) >> 1; if (batch[mid] < g + 1) lo = mid + 1; else hi = mid; }
    int end = lo;

    const float* hsrc = (f < HID) ? h1 : h2;
    int ff = (f < HID) ? f : f - HID;
    float sum = 0.f, mx = 0.f;  // h >= 0 post-relu
    for (int n = start + way; n < end; n += 4) {
        float v = hsrc[(size_t)n * HID + ff];
        sum += v;
        mx = fmaxf(mx, v);
    }
    __shared__ float rsum[4][192];
    __shared__ float rmax[4][192];
    rsum[way][f] = sum;
    rmax[way][f] = mx;
    __syncthreads();
    if (way == 0) {
        sum = rsum[0][f] + rsum[1][f] + rsum[2][f] + rsum[3][f];
        mx = fmaxf(fmaxf(rmax[0][f], rmax[1][f]), fmaxf(rmax[2][f], rmax[3][f]));
        float cnt = (float)(end - start);
        float mean = sum / fmaxf(cnt, 1.0f);
        rsum[0][f] = mean * Wg[f] + mx * Wg[192 + f];
    }
    __syncthreads();
    if (tid < 64) {
        float acc = rsum[0][tid] + rsum[0][tid + 64] + rsum[0][tid + 128];
#pragma unroll
        for (int m = 32; m; m >>= 1) acc += __shfl_down(acc, m, 64);
        if (tid == 0) out[g] = acc + bg[0];
    }
}

extern "C" void kernel_launch(void* const* d_in, const int* in_sizes, int n_in,
                              void* d_out, int out_size, void* d_ws, size_t ws_size,
                              hipStream_t stream) {
    const float* x    = (const float*)d_in[0];
    const int*   ei   = (const int*)d_in[1];
    const int*   srcp = ei;
    const int*   dstp = ei + NE;
    const int*   batch = (const int*)d_in[2];
    const float* W1 = (const float*)d_in[3];
    const float* b1 = (const float*)d_in[4];
    const float* W2 = (const float*)d_in[5];
    const float* b2 = (const float*)d_in[6];
    const float* Wn = (const float*)d_in[7];
    const float* bn = (const float*)d_in[8];
    const float* Wg = (const float*)d_in[9];
    const float* bg = (const float*)d_in[10];
    float* out = (float*)d_out;

    char* p = (char*)d_ws;
    auto alloc = [&](size_t bytes) {
        char* r = p;
        p += (bytes + 255) & ~(size_t)255;
        return (void*)r;
    };
    float*  dis   = (float*)alloc(NN * 4);
    int*    off   = (int*)alloc((NN + 1) * 4);
    int*    cur   = (int*)alloc(NN * 4);
    int*    bsum  = (int*)alloc(128 * 4);
    int2*   ssrcw = (int2*)alloc((size_t)NE * 8);
    __half* Ah    = (__half*)alloc((size_t)NN * HID * 2);
    float*  H1    = (float*)alloc((size_t)NN * HID * 4);
    float*  H2    = (float*)alloc((size_t)NN * HID * 4);

    const int TPB = 256;
    const int nScan = NN + 1;
    const int nbScan = (nScan + 1023) / 1024;    // 98

    // CSR prelude
    k_zero<<<(NN + TPB) / TPB, TPB, 0, stream>>>(off, cur);
    k_hist<<<(NE + TPB - 1) / TPB, TPB, 0, stream>>>(dstp, off);
    k_scan1<<<nbScan, 256, 0, stream>>>(off, bsum, nScan);
    k_scan2<<<1, 128, 0, stream>>>(bsum, nbScan);
    k_scan3<<<nbScan, 256, 0, stream>>>(off, bsum, nScan);
    k_dis<<<(NN + TPB - 1) / TPB, TPB, 0, stream>>>(off, dis);

    // FUSED: gemm1 (blocks 0..1562)  ∥  reorder (blocks 1563..7812)
    k_gemm1_reorder<<<GEMM1_BLOCKS + REORDER_BLOCKS, 256, 0, stream>>>(
        x, W1, Ah, srcp, dstp, off, cur, dis, ssrcw);

    const int aggThreads = NN * 32;
    float* nodeOut = out + NG;

    // conv1 aggregate: H1 = relu(agg(Ah) + b1) ; nodeOut = bn + H1.Wn[:96]
    k_agg<1><<<(aggThreads + TPB - 1) / TPB, TPB, 0, stream>>>(Ah, ssrcw, off, dis, b1, Wn, bn, H1, nodeOut);

    // conv2: Ah = fp16(H1@W2) ; H2 = relu(agg(Ah) + b2) ; nodeOut += H2.Wn[96:]
    k_gemm<HID><<<(NN + 63) / 64, 256, 0, stream>>>(H1, W2, Ah);
    k_agg<2><<<(aggThreads + TPB - 1) / TPB, TPB, 0, stream>>>(Ah, ssrcw, off, dis, b2, Wn, bn, H2, nodeOut);

    // pooling + graph head
    k_pool<<<NG, 768, 0, stream>>>(H1, H2, batch, Wg, bg, out);
}